// Round 17
// baseline (79.200 us; speedup 1.0000x reference)
//
#include <hip/hip_runtime.h>
#include <hip/hip_bf16.h>
#include <math.h>

#define DIMX 1024
#define SEQ  1024
#define HD   64
#define QH   2
#define TH   14
#define QKVN 2688   // 3*896
#define LN_EPS 1e-5f
#define NB_F2B 4736
#define NB_QPREP 1024
#define NB_XT 32

typedef __bf16 bf16x8 __attribute__((ext_vector_type(8)));
typedef float  f32x4  __attribute__((ext_vector_type(4)));
typedef unsigned short u16x8 __attribute__((ext_vector_type(8)));

__device__ inline unsigned short f2b_rne(float f) {
  unsigned int u = __float_as_uint(f);
  unsigned int r = (u + 0x7FFF + ((u >> 16) & 1)) >> 16;
  return (unsigned short)r;
}
__device__ inline float b2f(unsigned short u) {
  return __uint_as_float((unsigned int)u << 16);
}

__device__ inline float waveRedSum(float v) {
  #pragma unroll
  for (int off = 32; off; off >>= 1) v += __shfl_xor(v, off, 64);
  return v;
}

// ---------------- prep: f2b converts | quantum prep | x^T for quantum V ----------------
__global__ __launch_bounds__(256) void k_prep(
    const float* __restrict__ x, const float* __restrict__ qsW,
    const float* __restrict__ qsb, const float* __restrict__ lng,
    const float* __restrict__ lnb, const float* __restrict__ qfreq,
    const float* __restrict__ qshift,
    const float* __restrict__ wq, const float* __restrict__ wk,
    const float* __restrict__ wv, const float* __restrict__ wo,
    unsigned short* __restrict__ x_bf, unsigned short* __restrict__ wqkv_bf,
    unsigned short* __restrict__ wo_bf,
    unsigned short* __restrict__ qcs, unsigned short* __restrict__ kcs,
    unsigned short* __restrict__ xt) {
  __shared__ float xrow2[2][HD];
  __shared__ float redm[2][2], redv[2][2];
  __shared__ float qsv2[2][128];
  __shared__ unsigned short ttile[64][72];
  int t = threadIdx.x;
  int bid = blockIdx.x;
  if (bid < NB_F2B) {
    long i = ((long)bid * 256 + t) * 4;
    float4 v;
    unsigned short* dst;
    if (i < 1048576) {
      v = *reinterpret_cast<const float4*>(x + i);
      dst = x_bf + i;
    } else if (i < 3801088) {
      long j = i - 1048576;
      const float* s = (j < 917504) ? wq + j
                     : (j < 1835008) ? wk + (j - 917504)
                                     : wv + (j - 1835008);
      v = *reinterpret_cast<const float4*>(s);
      dst = wqkv_bf + j;
    } else {
      long j = i - 3801088;
      v = *reinterpret_cast<const float4*>(wo + j);
      dst = wo_bf + j;
    }
    ushort4 o;
    o.x = f2b_rne(v.x); o.y = f2b_rne(v.y); o.z = f2b_rne(v.z); o.w = f2b_rne(v.w);
    *reinterpret_cast<ushort4*>(dst) = o;
  } else if (bid < NB_F2B + NB_QPREP) {
    int half = t >> 7, o = t & 127;
    int row = (bid - NB_F2B) * 2 + half;
    int h = row >> 10, i = row & 1023;
    if (o < HD) xrow2[half][o] = x[i * DIMX + h * HD + o];
    __syncthreads();
    float s = qsb[o];
    #pragma unroll
    for (int d = 0; d < HD; d += 4) {
      float4 w = *reinterpret_cast<const float4*>(qsW + o * HD + d);
      float4 xv = *reinterpret_cast<const float4*>(&xrow2[half][d]);
      s += xv.x * w.x + xv.y * w.y + xv.z * w.z + xv.w * w.w;
    }
    int wid = (o >> 6), lane = o & 63;
    float ws = waveRedSum(s);
    if (lane == 0) redm[half][wid] = ws;
    __syncthreads();
    float mu = (redm[half][0] + redm[half][1]) * (1.0f / 128.0f);
    float dv = s - mu;
    float ws2 = waveRedSum(dv * dv);
    if (lane == 0) redv[half][wid] = ws2;
    __syncthreads();
    float var = (redv[half][0] + redv[half][1]) * (1.0f / 128.0f);
    float y = dv * rsqrtf(var + LN_EPS) * lng[o] + lnb[o];
    qsv2[half][o] = tanhf(y);
    __syncthreads();
    float freq = qfreq[h], shift = qshift[h];
    size_t base = ((size_t)h * 1024 + i) * 128;
    if (o < HD) {
      float amp = qsv2[half][o];
      float a = qsv2[half][64 + o] * freq + shift;
      float sn, cs;
      __sincosf(a, &sn, &cs);
      qcs[base + o]      = f2b_rne(amp * cs);
      qcs[base + 64 + o] = f2b_rne(amp * sn);
    } else {
      int d = o - 64;
      float amp = qsv2[half][d];
      float bAng = qsv2[half][64 + d] * freq;
      float sn, cs;
      __sincosf(bAng, &sn, &cs);
      kcs[base + d]      = f2b_rne(amp * cs);
      kcs[base + 64 + d] = f2b_rne(amp * sn);
    }
  } else {
    int b = bid - (NB_F2B + NB_QPREP);
    int h = b >> 4, kv0 = (b & 15) * 64;
    #pragma unroll
    for (int pass = 0; pass < 2; ++pass) {
      int s = pass * 256 + t;
      int r = s >> 3, c8 = (s & 7) * 8;
      const float* src = x + (size_t)(kv0 + r) * DIMX + h * 64 + c8;
      float4 a = *reinterpret_cast<const float4*>(src);
      float4 b4 = *reinterpret_cast<const float4*>(src + 4);
      ushort4 o1, o2;
      o1.x = f2b_rne(a.x);  o1.y = f2b_rne(a.y);  o1.z = f2b_rne(a.z);  o1.w = f2b_rne(a.w);
      o2.x = f2b_rne(b4.x); o2.y = f2b_rne(b4.y); o2.z = f2b_rne(b4.z); o2.w = f2b_rne(b4.w);
      *reinterpret_cast<ushort4*>(&ttile[r][c8]) = o1;
      *reinterpret_cast<ushort4*>(&ttile[r][c8 + 4]) = o2;
    }
    __syncthreads();
    #pragma unroll
    for (int pass = 0; pass < 2; ++pass) {
      int s = pass * 256 + t;
      int d = s >> 3, k8 = (s & 7) * 8;
      u16x8 o;
      #pragma unroll
      for (int j = 0; j < 8; ++j) o[j] = ttile[k8 + j][d];
      *reinterpret_cast<u16x8*>(xt + (size_t)h * 65536 + (size_t)d * 1024 + kv0 + k8) = o;
    }
  }
}

// ---------------- 64x64 GEMM device body: BK=128, global_load_lds + 16-slot swizzle --
template <int HAS_BIAS, int BF16_OUT>
__device__ __forceinline__ void dev_gemm64(
    char* smem,
    const unsigned short* __restrict__ A, const unsigned short* __restrict__ B,
    void* __restrict__ Cv, const float* __restrict__ bias,
    unsigned short* __restrict__ vtp,
    int bx, int by, int K, int lda, int ldb, int ldc) {
  unsigned short* As = (unsigned short*)smem;     // [64][128]
  unsigned short* Bs = As + 64 * 128;
  int t = threadIdx.x, lane = t & 63, w = t >> 6;
  int wr = w >> 1, wc = w & 1;
  int g = lane >> 4, li = lane & 15;
  int mb = by * 64, nb = bx * 64;
  int rstg = t >> 4;            // 0..15
  int cs = t & 15;              // col16 slot
  f32x4 acc[2][2] = {};
  for (int kb = 0; kb < K; kb += 128) {
    __syncthreads();
    #pragma unroll
    for (int i = 0; i < 4; ++i) {
      int row = i * 16 + rstg;
      int csw = ((cs ^ (row & 7)) * 8);
      __builtin_amdgcn_global_load_lds(
          (const __attribute__((address_space(1))) unsigned int*)(A + (size_t)(mb + row) * lda + kb + csw),
          (__attribute__((address_space(3))) unsigned int*)(As + row * 128 + cs * 8), 16, 0, 0);
      __builtin_amdgcn_global_load_lds(
          (const __attribute__((address_space(1))) unsigned int*)(B + (size_t)(nb + row) * ldb + kb + csw),
          (__attribute__((address_space(3))) unsigned int*)(Bs + row * 128 + cs * 8), 16, 0, 0);
    }
    __syncthreads();
    #pragma unroll
    for (int kk = 0; kk < 4; ++kk) {
      bf16x8 af[2], bfr[2];
      #pragma unroll
      for (int m = 0; m < 2; ++m) {
        int r = wr * 32 + m * 16 + li;
        int cb = kk * 4 + g;
        af[m] = *reinterpret_cast<const bf16x8*>(&As[r * 128 + ((cb ^ (r & 7)) * 8)]);
      }
      #pragma unroll
      for (int n = 0; n < 2; ++n) {
        int r = wc * 32 + n * 16 + li;
        int cb = kk * 4 + g;
        bfr[n] = *reinterpret_cast<const bf16x8*>(&Bs[r * 128 + ((cb ^ (r & 7)) * 8)]);
      }
      #pragma unroll
      for (int m = 0; m < 2; ++m)
        #pragma unroll
        for (int n = 0; n < 2; ++n)
          acc[m][n] = __builtin_amdgcn_mfma_f32_16x16x32_bf16(af[m], bfr[n], acc[m][n], 0, 0, 0);
    }
  }
  if (vtp != nullptr && nb >= 1792) {
    #pragma unroll
    for (int m = 0; m < 2; ++m) {
      int row0 = mb + wr * 32 + m * 16 + g * 4;
      #pragma unroll
      for (int n = 0; n < 2; ++n) {
        int colrel = nb - 1792 + wc * 32 + n * 16 + li;
        #pragma unroll
        for (int r = 0; r < 4; ++r)
          vtp[(size_t)colrel * 1024 + row0 + r] = f2b_rne(acc[m][n][r]);
      }
    }
    return;
  }
  #pragma unroll
  for (int m = 0; m < 2; ++m) {
    int row0 = mb + wr * 32 + m * 16 + g * 4;
    #pragma unroll
    for (int n = 0; n < 2; ++n) {
      int col = nb + wc * 32 + n * 16 + li;
      float bval = HAS_BIAS ? bias[col] : 0.0f;
      #pragma unroll
      for (int r = 0; r < 4; ++r) {
        size_t idx = (size_t)(row0 + r) * ldc + col;
        if (BF16_OUT) ((unsigned short*)Cv)[idx] = f2b_rne(acc[m][n][r] + bval);
        else          ((float*)Cv)[idx] = acc[m][n][r] + bval;
      }
    }
  }
}

// ---------------- QKV GEMM (672 blocks, XCD-chunked; V tiles -> vt transposed) -------
__global__ __launch_bounds__(256) void k_qkv(
    const unsigned short* __restrict__ x_bf, const unsigned short* __restrict__ wqkv,
    unsigned short* __restrict__ qkv, unsigned short* __restrict__ vt) {
  __shared__ __align__(16) char smem[32768];
  int bid = blockIdx.x;
  int swz = (bid & 7) * 84 + (bid >> 3);       // 672 = 8*84
  int by = swz / 42, bx = swz % 42;
  dev_gemm64<0, 1>(smem, x_bf, wqkv, qkv, nullptr, vt, bx, by, DIMX, DIMX, DIMX, QKVN);
}

// ---------------- attention, m97-style (R13 geometry): glds staging, batch softmax ---
// Phase 1: NT x {bar; glds K [64][DQK] (swizzled); bar; QK^T}. One softmax pass.
// Phase 3: NT x {bar; glds V [64][64]; bar; Ps (wave-local) + PV}. V reuses K buffer.
// pout = UNNORMALIZED bf16 partials; pml = f32 (m,l).
template <int DQK, int NT>
__device__ __forceinline__ void dev_fattn4(
    char* smem,
    const unsigned short* __restrict__ Qp, int ldq,
    const unsigned short* __restrict__ Kp, int ldk,
    const unsigned short* __restrict__ Vp,       // [64][1024] bf16 (d-major)
    int q0, int kv0, int slot,
    unsigned short* __restrict__ pout, float* __restrict__ pml) {
  const int KREG = DQK / 32;
  const int NSLOT = DQK / 8;                 // 16B slots per K row (8 or 16)
  unsigned short* Ks = (unsigned short*)smem;  // [64][DQK]; V tile reuses as [64][64]
  unsigned short* Ps = Ks + 64 * DQK;          // [64][72]
  int t = threadIdx.x, lane = t & 63, w = t >> 6;
  int g = lane >> 4, li = lane & 15;

  // Q fragments straight to registers (lane li owns q-row q0 + w*16 + li)
  bf16x8 aq[KREG];
  #pragma unroll
  for (int kk = 0; kk < KREG; ++kk)
    aq[kk] = *reinterpret_cast<const bf16x8*>(
        Qp + (size_t)(q0 + w * 16 + li) * ldq + kk * 32 + g * 8);

  f32x4 s_all[NT][4] = {};

  // phase 1: QK^T
  {
    int rstg = t / NSLOT, cs = t % NSLOT;    // K rows: RPI=256/NSLOT per issue
    #pragma unroll
    for (int tile = 0; tile < NT; ++tile) {
      int j0 = kv0 + tile * 64;
      __syncthreads();                        // prior tile's K reads complete
      #pragma unroll
      for (int i = 0; i < NSLOT / 4; ++i) {   // 64/(256/NSLOT) issues
        int row = i * (256 / NSLOT) + rstg;
        int csw = ((cs ^ (row & 7)) * 8);
        __builtin_amdgcn_global_load_lds(
            (const __attribute__((address_space(1))) unsigned int*)(Kp + (size_t)(j0 + row) * ldk + csw),
            (__attribute__((address_space(3))) unsigned int*)(Ks + row * DQK + cs * 8), 16, 0, 0);
      }
      __syncthreads();                        // vmcnt drained -> K tile visible
      #pragma unroll
      for (int kk = 0; kk < KREG; ++kk) {
        #pragma unroll
        for (int n = 0; n < 4; ++n) {
          int r = n * 16 + li;
          int cb = kk * 4 + g;
          bf16x8 bk = *reinterpret_cast<const bf16x8*>(&Ks[r * DQK + ((cb ^ (r & 7)) * 8)]);
          s_all[tile][n] = __builtin_amdgcn_mfma_f32_16x16x32_bf16(aq[kk], bk, s_all[tile][n], 0, 0, 0);
        }
      }
    }
  }

  // phase 2: single softmax pass (block-local max; merge handles cross-split)
  float mrow[4], lrow[4];
  #pragma unroll
  for (int r = 0; r < 4; ++r) {
    float tm = -1e30f;
    #pragma unroll
    for (int tile = 0; tile < NT; ++tile)
      #pragma unroll
      for (int n = 0; n < 4; ++n) tm = fmaxf(tm, s_all[tile][n][r]);
    #pragma unroll
    for (int m = 1; m < 16; m <<= 1) tm = fmaxf(tm, __shfl_xor(tm, m, 64));
    float rs = 0.f;
    #pragma unroll
    for (int tile = 0; tile < NT; ++tile)
      #pragma unroll
      for (int n = 0; n < 4; ++n) {
        float p = __expf((s_all[tile][n][r] - tm) * 0.125f);
        s_all[tile][n][r] = p;
        rs += p;
      }
    #pragma unroll
    for (int m = 1; m < 16; m <<= 1) rs += __shfl_xor(rs, m, 64);
    mrow[r] = tm; lrow[r] = rs;
  }

  // phase 3: PV (V tiles staged into the same buffer, 64-wide)
  f32x4 acc_o[4] = {};
  {
    int rstg = t >> 3, cs = t & 7;
    #pragma unroll
    for (int tile = 0; tile < NT; ++tile) {
      int j0 = kv0 + tile * 64;
      __syncthreads();                        // prior reads (K last tile / V prev) done
      #pragma unroll
      for (int i = 0; i < 2; ++i) {
        int row = i * 32 + rstg;              // d index
        int csw = ((cs ^ (row & 7)) * 8);
        __builtin_amdgcn_global_load_lds(
            (const __attribute__((address_space(1))) unsigned int*)(Vp + (size_t)row * 1024 + j0 + csw),
            (__attribute__((address_space(3))) unsigned int*)(Ks + row * 64 + cs * 8), 16, 0, 0);
      }
      __syncthreads();                        // V tile visible
      #pragma unroll
      for (int n = 0; n < 4; ++n)
        #pragma unroll
        for (int r = 0; r < 4; ++r)
          Ps[(w * 16 + g * 4 + r) * 72 + n * 16 + li] = f2b_rne(s_all[tile][n][r]);
      #pragma unroll
      for (int kk = 0; kk < 2; ++kk) {
        bf16x8 ap = *reinterpret_cast<const bf16x8*>(&Ps[(w * 16 + li) * 72 + kk * 32 + g * 8]);
        #pragma unroll
        for (int n = 0; n < 4; ++n) {
          int r = n * 16 + li;
          int cb = kk * 4 + g;
          bf16x8 bv = *reinterpret_cast<const bf16x8*>(&Ks[r * 64 + ((cb ^ (r & 7)) * 8)]);
          acc_o[n] = __builtin_amdgcn_mfma_f32_16x16x32_bf16(ap, bv, acc_o[n], 0, 0, 0);
        }
      }
    }
  }

  size_t rowbase = (size_t)slot * 1024;
  #pragma unroll
  for (int r = 0; r < 4; ++r) {
    int qr = q0 + w * 16 + g * 4 + r;
    #pragma unroll
    for (int n = 0; n < 4; ++n)
      pout[(rowbase + qr) * 64 + n * 16 + li] = f2b_rne(acc_o[n][r]);
    if (li == 0) {
      pml[(rowbase + qr) * 2 + 0] = mrow[r];
      pml[(rowbase + qr) * 2 + 1] = lrow[r];
    }
  }
}

// blocks (XCD-chunked over 1152): logical 0..255 quantum, 256..1151 trad
__global__ __launch_bounds__(256) void k_attn_all(
    const unsigned short* __restrict__ qcs, const unsigned short* __restrict__ kcs,
    const unsigned short* __restrict__ xt, const unsigned short* __restrict__ qkv,
    const unsigned short* __restrict__ vt,
    unsigned short* __restrict__ pout, float* __restrict__ pml) {
  __shared__ __align__(16) char smem[25600];   // quantum 25600, trad 17408
  int bid = blockIdx.x;
  int l = (bid & 7) * 144 + (bid >> 3);        // 1152 = 8*144
  if (l < 256) {
    int qt = l & 15, h = (l >> 4) & 1, split = l >> 5;     // 8 splits, NT=2
    dev_fattn4<128, 2>(smem, qcs + (size_t)h * SEQ * 128, 128,
                       kcs + (size_t)h * SEQ * 128, 128,
                       xt + (size_t)h * 65536,
                       qt * 64, split * 128, h * 8 + split, pout, pml);
  } else {
    int b2 = l - 256;
    int qt = b2 & 15, hs = b2 >> 4;                        // hs 0..55
    int h = hs % 14, split = hs / 14;                      // 4 splits, NT=4
    dev_fattn4<64, 4>(smem, qkv + h * 64, QKVN,
                      qkv + 896 + h * 64, QKVN,
                      vt + (size_t)h * 65536,
                      qt * 64, split * 256, 16 + h * 4 + split, pout, pml);
  }
}

// ---------------- merge kv-split partials (bf16 pout) -> concat bf16 ----------------
__global__ __launch_bounds__(256) void k_fmerge(
    const unsigned short* __restrict__ pout, const float* __restrict__ pml,
    unsigned short* __restrict__ concat) {
  int rq = blockIdx.x * 4 + (threadIdx.x >> 6);
  int lh = rq >> 10, q = rq & 1023;
  int d = threadIdx.x & 63;
  int s0 = (lh < 2) ? lh * 8 : 16 + (lh - 2) * 4;
  int ns = (lh < 2) ? 8 : 4;
  float m_s[8], l_s[8];
  float M = -1e30f;
  #pragma unroll
  for (int s = 0; s < 8; ++s) {
    if (s < ns) {
      size_t rb = (size_t)(s0 + s) * 1024 + q;
      m_s[s] = pml[rb * 2 + 0];
      l_s[s] = pml[rb * 2 + 1];
      M = fmaxf(M, m_s[s]);
    }
  }
  float num = 0.f, den = 0.f;
  #pragma unroll
  for (int s = 0; s < 8; ++s) {
    if (s < ns) {
      float wgt = __expf((m_s[s] - M) * 0.125f);
      num += wgt * b2f(pout[((size_t)(s0 + s) * 1024 + q) * 64 + d]);
      den += wgt * l_s[s];
    }
  }
  concat[(size_t)q * DIMX + lh * 64 + d] = f2b_rne(num / den);
}

// ---------------- output projection: 32x64 tiles, 512 blocks, BK=128 ----------------
__global__ __launch_bounds__(256) void k_oproj(
    const unsigned short* __restrict__ A, const unsigned short* __restrict__ B,
    float* __restrict__ C, const float* __restrict__ bias) {
  __shared__ unsigned short As[32 * 128];
  __shared__ unsigned short Bs[64 * 128];
  int bid = blockIdx.x;
  int swz = (bid & 7) * 64 + (bid >> 3);       // 512 = 8*64
  int by = swz >> 4, bx = swz & 15;
  int t = threadIdx.x, lane = t & 63, w = t >> 6;
  int wr = w & 1, wc = w >> 1;
  int g = lane >> 4, li = lane & 15;
  int mb = by * 32, nb = bx * 64;
  int rstg = t >> 4, cs = t & 15;
  f32x4 acc[2] = {};
  for (int kb = 0; kb < DIMX; kb += 128) {
    __syncthreads();
    #pragma unroll
    for (int i = 0; i < 2; ++i) {
      int row = i * 16 + rstg;
      int csw = ((cs ^ (row & 7)) * 8);
      __builtin_amdgcn_global_load_lds(
          (const __attribute__((address_space(1))) unsigned int*)(A + (size_t)(mb + row) * DIMX + kb + csw),
          (__attribute__((address_space(3))) unsigned int*)(As + row * 128 + cs * 8), 16, 0, 0);
    }
    #pragma unroll
    for (int i = 0; i < 4; ++i) {
      int row = i * 16 + rstg;
      int csw = ((cs ^ (row & 7)) * 8);
      __builtin_amdgcn_global_load_lds(
          (const __attribute__((address_space(1))) unsigned int*)(B + (size_t)(nb + row) * DIMX + kb + csw),
          (__attribute__((address_space(3))) unsigned int*)(Bs + row * 128 + cs * 8), 16, 0, 0);
    }
    __syncthreads();
    #pragma unroll
    for (int kk = 0; kk < 4; ++kk) {
      int cb = kk * 4 + g;
      int ra = wr * 16 + li;
      bf16x8 af = *reinterpret_cast<const bf16x8*>(&As[ra * 128 + ((cb ^ (ra & 7)) * 8)]);
      #pragma unroll
      for (int n = 0; n < 2; ++n) {
        int rb = wc * 32 + n * 16 + li;
        bf16x8 bfr = *reinterpret_cast<const bf16x8*>(&Bs[rb * 128 + ((cb ^ (rb & 7)) * 8)]);
        acc[n] = __builtin_amdgcn_mfma_f32_16x16x32_bf16(af, bfr, acc[n], 0, 0, 0);
      }
    }
  }
  int row0 = mb + wr * 16 + g * 4;
  #pragma unroll
  for (int n = 0; n < 2; ++n) {
    int col = nb + wc * 32 + n * 16 + li;
    float bval = bias[col];
    #pragma unroll
    for (int r = 0; r < 4; ++r)
      C[(size_t)(row0 + r) * DIMX + col] = acc[n][r] + bval;
  }
}

extern "C" void kernel_launch(void* const* d_in, const int* in_sizes, int n_in,
                              void* d_out, int out_size, void* d_ws, size_t ws_size,
                              hipStream_t stream) {
  const float* x      = (const float*)d_in[0];
  const float* qsW    = (const float*)d_in[1];
  const float* qsb    = (const float*)d_in[2];
  const float* lng    = (const float*)d_in[3];
  const float* lnb    = (const float*)d_in[4];
  const float* qfreq  = (const float*)d_in[5];
  const float* qshift = (const float*)d_in[6];
  const float* Wq     = (const float*)d_in[7];
  const float* Wk     = (const float*)d_in[8];
  const float* Wv     = (const float*)d_in[9];
  const float* Wo     = (const float*)d_in[10];
  const float* bo     = (const float*)d_in[11];
  float* out = (float*)d_out;

  char* ws = (char*)d_ws;
  size_t off = 0;
  auto alloc = [&](size_t bytes) { char* p = ws + off; off += (bytes + 255) & ~(size_t)255; return p; };
  unsigned short* x_bf      = (unsigned short*)alloc((size_t)SEQ * DIMX * 2);
  unsigned short* wqkv_bf   = (unsigned short*)alloc((size_t)QKVN * DIMX * 2);
  unsigned short* wo_bf     = (unsigned short*)alloc((size_t)DIMX * DIMX * 2);
  unsigned short* concat_bf = (unsigned short*)alloc((size_t)SEQ * DIMX * 2);
  unsigned short* qkv_bf    = (unsigned short*)alloc((size_t)SEQ * QKVN * 2);
  unsigned short* qcs       = (unsigned short*)alloc((size_t)QH * SEQ * 128 * 2);
  unsigned short* kcs       = (unsigned short*)alloc((size_t)QH * SEQ * 128 * 2);
  unsigned short* vt        = (unsigned short*)alloc((size_t)TH * HD * SEQ * 2);
  unsigned short* xt        = (unsigned short*)alloc((size_t)QH * HD * SEQ * 2);
  unsigned short* pout      = (unsigned short*)alloc((size_t)72 * SEQ * 64 * 2);
  float*          pml       = (float*)alloc((size_t)72 * SEQ * 2 * 4);

  // 1. prep: converts + quantum prep + x^T
  k_prep<<<NB_F2B + NB_QPREP + NB_XT, 256, 0, stream>>>(
      x, qsW, qsb, lng, lnb, qfreq, qshift, Wq, Wk, Wv, Wo,
      x_bf, wqkv_bf, wo_bf, qcs, kcs, xt);

  // 2. QKV projection (V tiles straight to vt transposed)
  k_qkv<<<672, 256, 0, stream>>>(x_bf, wqkv_bf, qkv_bf, vt);

  // 3. all attention (quantum + trad), R13 geometry, bf16 partials
  k_attn_all<<<1152, 256, 0, stream>>>(qcs, kcs, xt, qkv_bf, vt, pout, pml);

  // 4. merge partials
  k_fmerge<<<16 * SEQ / 4, 256, 0, stream>>>(pout, pml, concat_bf);

  // 5. output projection + bias
  k_oproj<<<512, 256, 0, stream>>>(concat_bf, wo_bf, out, bo);
}

// Round 18
// 73.655 us; speedup vs baseline: 1.0753x; 1.0753x over previous
//
#include <hip/hip_runtime.h>
#include <hip/hip_bf16.h>
#include <math.h>

#define DIMX 1024
#define SEQ  1024
#define HD   64
#define QH   2
#define TH   14
#define QKVN 2688   // 3*896
#define LN_EPS 1e-5f
#define NB_F2B 4736
#define NB_QPREP 1024
#define NB_XT 32

typedef __bf16 bf16x8 __attribute__((ext_vector_type(8)));
typedef float  f32x4  __attribute__((ext_vector_type(4)));
typedef unsigned short u16x8 __attribute__((ext_vector_type(8)));

__device__ inline unsigned short f2b_rne(float f) {
  unsigned int u = __float_as_uint(f);
  unsigned int r = (u + 0x7FFF + ((u >> 16) & 1)) >> 16;
  return (unsigned short)r;
}

__device__ inline float waveRedSum(float v) {
  #pragma unroll
  for (int off = 32; off; off >>= 1) v += __shfl_xor(v, off, 64);
  return v;
}

// ---------------- prep: f2b converts | quantum prep | x^T for quantum V ----------------
__global__ __launch_bounds__(256) void k_prep(
    const float* __restrict__ x, const float* __restrict__ qsW,
    const float* __restrict__ qsb, const float* __restrict__ lng,
    const float* __restrict__ lnb, const float* __restrict__ qfreq,
    const float* __restrict__ qshift,
    const float* __restrict__ wq, const float* __restrict__ wk,
    const float* __restrict__ wv, const float* __restrict__ wo,
    unsigned short* __restrict__ x_bf, unsigned short* __restrict__ wqkv_bf,
    unsigned short* __restrict__ wo_bf,
    unsigned short* __restrict__ qcs, unsigned short* __restrict__ kcs,
    unsigned short* __restrict__ xt) {
  __shared__ float xrow2[2][HD];
  __shared__ float redm[2][2], redv[2][2];
  __shared__ float qsv2[2][128];
  __shared__ unsigned short ttile[64][72];
  int t = threadIdx.x;
  int bid = blockIdx.x;
  if (bid < NB_F2B) {
    long i = ((long)bid * 256 + t) * 4;
    float4 v;
    unsigned short* dst;
    if (i < 1048576) {
      v = *reinterpret_cast<const float4*>(x + i);
      dst = x_bf + i;
    } else if (i < 3801088) {
      long j = i - 1048576;
      const float* s = (j < 917504) ? wq + j
                     : (j < 1835008) ? wk + (j - 917504)
                                     : wv + (j - 1835008);
      v = *reinterpret_cast<const float4*>(s);
      dst = wqkv_bf + j;
    } else {
      long j = i - 3801088;
      v = *reinterpret_cast<const float4*>(wo + j);
      dst = wo_bf + j;
    }
    ushort4 o;
    o.x = f2b_rne(v.x); o.y = f2b_rne(v.y); o.z = f2b_rne(v.z); o.w = f2b_rne(v.w);
    *reinterpret_cast<ushort4*>(dst) = o;
  } else if (bid < NB_F2B + NB_QPREP) {
    int half = t >> 7, o = t & 127;
    int row = (bid - NB_F2B) * 2 + half;
    int h = row >> 10, i = row & 1023;
    if (o < HD) xrow2[half][o] = x[i * DIMX + h * HD + o];
    __syncthreads();
    float s = qsb[o];
    #pragma unroll
    for (int d = 0; d < HD; d += 4) {
      float4 w = *reinterpret_cast<const float4*>(qsW + o * HD + d);
      float4 xv = *reinterpret_cast<const float4*>(&xrow2[half][d]);
      s += xv.x * w.x + xv.y * w.y + xv.z * w.z + xv.w * w.w;
    }
    int wid = (o >> 6), lane = o & 63;
    float ws = waveRedSum(s);
    if (lane == 0) redm[half][wid] = ws;
    __syncthreads();
    float mu = (redm[half][0] + redm[half][1]) * (1.0f / 128.0f);
    float dv = s - mu;
    float ws2 = waveRedSum(dv * dv);
    if (lane == 0) redv[half][wid] = ws2;
    __syncthreads();
    float var = (redv[half][0] + redv[half][1]) * (1.0f / 128.0f);
    float y = dv * rsqrtf(var + LN_EPS) * lng[o] + lnb[o];
    qsv2[half][o] = tanhf(y);
    __syncthreads();
    float freq = qfreq[h], shift = qshift[h];
    size_t base = ((size_t)h * 1024 + i) * 128;
    if (o < HD) {
      float amp = qsv2[half][o];
      float a = qsv2[half][64 + o] * freq + shift;
      float sn, cs;
      __sincosf(a, &sn, &cs);
      qcs[base + o]      = f2b_rne(amp * cs);
      qcs[base + 64 + o] = f2b_rne(amp * sn);
    } else {
      int d = o - 64;
      float amp = qsv2[half][d];
      float bAng = qsv2[half][64 + d] * freq;
      float sn, cs;
      __sincosf(bAng, &sn, &cs);
      kcs[base + d]      = f2b_rne(amp * cs);
      kcs[base + 64 + d] = f2b_rne(amp * sn);
    }
  } else {
    int b = bid - (NB_F2B + NB_QPREP);
    int h = b >> 4, kv0 = (b & 15) * 64;
    #pragma unroll
    for (int pass = 0; pass < 2; ++pass) {
      int s = pass * 256 + t;
      int r = s >> 3, c8 = (s & 7) * 8;
      const float* src = x + (size_t)(kv0 + r) * DIMX + h * 64 + c8;
      float4 a = *reinterpret_cast<const float4*>(src);
      float4 b4 = *reinterpret_cast<const float4*>(src + 4);
      ushort4 o1, o2;
      o1.x = f2b_rne(a.x);  o1.y = f2b_rne(a.y);  o1.z = f2b_rne(a.z);  o1.w = f2b_rne(a.w);
      o2.x = f2b_rne(b4.x); o2.y = f2b_rne(b4.y); o2.z = f2b_rne(b4.z); o2.w = f2b_rne(b4.w);
      *reinterpret_cast<ushort4*>(&ttile[r][c8]) = o1;
      *reinterpret_cast<ushort4*>(&ttile[r][c8 + 4]) = o2;
    }
    __syncthreads();
    #pragma unroll
    for (int pass = 0; pass < 2; ++pass) {
      int s = pass * 256 + t;
      int d = s >> 3, k8 = (s & 7) * 8;
      u16x8 o;
      #pragma unroll
      for (int j = 0; j < 8; ++j) o[j] = ttile[k8 + j][d];
      *reinterpret_cast<u16x8*>(xt + (size_t)h * 65536 + (size_t)d * 1024 + kv0 + k8) = o;
    }
  }
}

// ---------------- 64x64 GEMM device body: BK=128, global_load_lds + 16-slot swizzle --
template <int HAS_BIAS, int BF16_OUT>
__device__ __forceinline__ void dev_gemm64(
    char* smem,
    const unsigned short* __restrict__ A, const unsigned short* __restrict__ B,
    void* __restrict__ Cv, const float* __restrict__ bias,
    unsigned short* __restrict__ vtp,
    int bx, int by, int K, int lda, int ldb, int ldc) {
  unsigned short* As = (unsigned short*)smem;     // [64][128]
  unsigned short* Bs = As + 64 * 128;
  int t = threadIdx.x, lane = t & 63, w = t >> 6;
  int wr = w >> 1, wc = w & 1;
  int g = lane >> 4, li = lane & 15;
  int mb = by * 64, nb = bx * 64;
  int rstg = t >> 4;            // 0..15
  int cs = t & 15;              // col16 slot
  f32x4 acc[2][2] = {};
  for (int kb = 0; kb < K; kb += 128) {
    __syncthreads();
    #pragma unroll
    for (int i = 0; i < 4; ++i) {
      int row = i * 16 + rstg;
      int csw = ((cs ^ (row & 7)) * 8);
      __builtin_amdgcn_global_load_lds(
          (const __attribute__((address_space(1))) unsigned int*)(A + (size_t)(mb + row) * lda + kb + csw),
          (__attribute__((address_space(3))) unsigned int*)(As + row * 128 + cs * 8), 16, 0, 0);
      __builtin_amdgcn_global_load_lds(
          (const __attribute__((address_space(1))) unsigned int*)(B + (size_t)(nb + row) * ldb + kb + csw),
          (__attribute__((address_space(3))) unsigned int*)(Bs + row * 128 + cs * 8), 16, 0, 0);
    }
    __syncthreads();
    #pragma unroll
    for (int kk = 0; kk < 4; ++kk) {
      bf16x8 af[2], bfr[2];
      #pragma unroll
      for (int m = 0; m < 2; ++m) {
        int r = wr * 32 + m * 16 + li;
        int cb = kk * 4 + g;
        af[m] = *reinterpret_cast<const bf16x8*>(&As[r * 128 + ((cb ^ (r & 7)) * 8)]);
      }
      #pragma unroll
      for (int n = 0; n < 2; ++n) {
        int r = wc * 32 + n * 16 + li;
        int cb = kk * 4 + g;
        bfr[n] = *reinterpret_cast<const bf16x8*>(&Bs[r * 128 + ((cb ^ (r & 7)) * 8)]);
      }
      #pragma unroll
      for (int m = 0; m < 2; ++m)
        #pragma unroll
        for (int n = 0; n < 2; ++n)
          acc[m][n] = __builtin_amdgcn_mfma_f32_16x16x32_bf16(af[m], bfr[n], acc[m][n], 0, 0, 0);
    }
  }
  if (vtp != nullptr && nb >= 1792) {
    #pragma unroll
    for (int m = 0; m < 2; ++m) {
      int row0 = mb + wr * 32 + m * 16 + g * 4;
      #pragma unroll
      for (int n = 0; n < 2; ++n) {
        int colrel = nb - 1792 + wc * 32 + n * 16 + li;
        #pragma unroll
        for (int r = 0; r < 4; ++r)
          vtp[(size_t)colrel * 1024 + row0 + r] = f2b_rne(acc[m][n][r]);
      }
    }
    return;
  }
  #pragma unroll
  for (int m = 0; m < 2; ++m) {
    int row0 = mb + wr * 32 + m * 16 + g * 4;
    #pragma unroll
    for (int n = 0; n < 2; ++n) {
      int col = nb + wc * 32 + n * 16 + li;
      float bval = HAS_BIAS ? bias[col] : 0.0f;
      #pragma unroll
      for (int r = 0; r < 4; ++r) {
        size_t idx = (size_t)(row0 + r) * ldc + col;
        if (BF16_OUT) ((unsigned short*)Cv)[idx] = f2b_rne(acc[m][n][r] + bval);
        else          ((float*)Cv)[idx] = acc[m][n][r] + bval;
      }
    }
  }
}

// ---------------- QKV GEMM (672 blocks, XCD-chunked; V tiles -> vt transposed) -------
__global__ __launch_bounds__(256) void k_qkv(
    const unsigned short* __restrict__ x_bf, const unsigned short* __restrict__ wqkv,
    unsigned short* __restrict__ qkv, unsigned short* __restrict__ vt) {
  __shared__ __align__(16) char smem[32768];
  int bid = blockIdx.x;
  int swz = (bid & 7) * 84 + (bid >> 3);       // 672 = 8*84
  int by = swz / 42, bx = swz % 42;
  dev_gemm64<0, 1>(smem, x_bf, wqkv, qkv, nullptr, vt, bx, by, DIMX, DIMX, DIMX, QKVN);
}

// ---------------- attention, m97-style: single LDS buffer, glds staging, batch softmax
// Phase 1: NT x {bar; glds K-tile (swizzled); bar; QK^T MFMA}. Softmax in regs.
// Phase 2: NT x {bar; glds V-tile; bar; Ps write (wave-local); PV MFMA}. V reuses K buf.
template <int DQK, int NT>
__device__ __forceinline__ void dev_fattn4(
    char* smem,
    const unsigned short* __restrict__ Qp, int ldq,
    const unsigned short* __restrict__ Kp, int ldk,
    const unsigned short* __restrict__ Vp,       // [64][1024] bf16 (d-major)
    int q0, int kv0, int slot,
    float* __restrict__ pout, float* __restrict__ pml) {
  const int KREG = DQK / 32;
  const int NSLOT = DQK / 8;                 // 16B slots per K row (8 or 16)
  unsigned short* Ks = (unsigned short*)smem;  // [64][DQK]; V tile reuses as [64][64]
  unsigned short* Ps = Ks + 64 * DQK;          // [64][72]
  int t = threadIdx.x, lane = t & 63, w = t >> 6;
  int g = lane >> 4, li = lane & 15;

  // Q fragments straight to registers (lane li owns q-row q0 + w*16 + li)
  bf16x8 aq[KREG];
  #pragma unroll
  for (int kk = 0; kk < KREG; ++kk)
    aq[kk] = *reinterpret_cast<const bf16x8*>(
        Qp + (size_t)(q0 + w * 16 + li) * ldq + kk * 32 + g * 8);

  f32x4 s_all[NT][4] = {};

  // phase 1: QK^T
  {
    int rstg = t / NSLOT, cs = t % NSLOT;    // K rows: RPI=256/NSLOT per issue
    #pragma unroll
    for (int tile = 0; tile < NT; ++tile) {
      int j0 = kv0 + tile * 64;
      __syncthreads();                        // prior tile's K reads complete
      #pragma unroll
      for (int i = 0; i < NSLOT / 4; ++i) {   // 64/(256/NSLOT) issues
        int row = i * (256 / NSLOT) + rstg;
        int csw = ((cs ^ (row & 7)) * 8);
        __builtin_amdgcn_global_load_lds(
            (const __attribute__((address_space(1))) unsigned int*)(Kp + (size_t)(j0 + row) * ldk + csw),
            (__attribute__((address_space(3))) unsigned int*)(Ks + row * DQK + cs * 8), 16, 0, 0);
      }
      __syncthreads();                        // vmcnt drained -> K tile visible
      #pragma unroll
      for (int kk = 0; kk < KREG; ++kk) {
        #pragma unroll
        for (int n = 0; n < 4; ++n) {
          int r = n * 16 + li;
          int cb = kk * 4 + g;
          bf16x8 bk = *reinterpret_cast<const bf16x8*>(&Ks[r * DQK + ((cb ^ (r & 7)) * 8)]);
          s_all[tile][n] = __builtin_amdgcn_mfma_f32_16x16x32_bf16(aq[kk], bk, s_all[tile][n], 0, 0, 0);
        }
      }
    }
  }

  // phase 2: single softmax pass (block-local max; merge handles cross-split)
  float mrow[4], lrow[4];
  #pragma unroll
  for (int r = 0; r < 4; ++r) {
    float tm = -1e30f;
    #pragma unroll
    for (int tile = 0; tile < NT; ++tile)
      #pragma unroll
      for (int n = 0; n < 4; ++n) tm = fmaxf(tm, s_all[tile][n][r]);
    #pragma unroll
    for (int m = 1; m < 16; m <<= 1) tm = fmaxf(tm, __shfl_xor(tm, m, 64));
    float rs = 0.f;
    #pragma unroll
    for (int tile = 0; tile < NT; ++tile)
      #pragma unroll
      for (int n = 0; n < 4; ++n) {
        float p = __expf((s_all[tile][n][r] - tm) * 0.125f);
        s_all[tile][n][r] = p;
        rs += p;
      }
    #pragma unroll
    for (int m = 1; m < 16; m <<= 1) rs += __shfl_xor(rs, m, 64);
    mrow[r] = tm; lrow[r] = rs;
  }

  // phase 3: PV (V tiles staged into the same buffer, 64-wide)
  f32x4 acc_o[4] = {};
  {
    int rstg = t >> 3, cs = t & 7;
    #pragma unroll
    for (int tile = 0; tile < NT; ++tile) {
      int j0 = kv0 + tile * 64;
      __syncthreads();                        // prior reads (K last tile / V prev) done
      #pragma unroll
      for (int i = 0; i < 2; ++i) {
        int row = i * 32 + rstg;              // d index
        int csw = ((cs ^ (row & 7)) * 8);
        __builtin_amdgcn_global_load_lds(
            (const __attribute__((address_space(1))) unsigned int*)(Vp + (size_t)row * 1024 + j0 + csw),
            (__attribute__((address_space(3))) unsigned int*)(Ks + row * 64 + cs * 8), 16, 0, 0);
      }
      __syncthreads();                        // V tile visible
      #pragma unroll
      for (int n = 0; n < 4; ++n)
        #pragma unroll
        for (int r = 0; r < 4; ++r)
          Ps[(w * 16 + g * 4 + r) * 72 + n * 16 + li] = f2b_rne(s_all[tile][n][r]);
      #pragma unroll
      for (int kk = 0; kk < 2; ++kk) {
        bf16x8 ap = *reinterpret_cast<const bf16x8*>(&Ps[(w * 16 + li) * 72 + kk * 32 + g * 8]);
        #pragma unroll
        for (int n = 0; n < 4; ++n) {
          int r = n * 16 + li;
          int cb = kk * 4 + g;
          bf16x8 bv = *reinterpret_cast<const bf16x8*>(&Ks[r * 64 + ((cb ^ (r & 7)) * 8)]);
          acc_o[n] = __builtin_amdgcn_mfma_f32_16x16x32_bf16(ap, bv, acc_o[n], 0, 0, 0);
        }
      }
    }
  }

  size_t rowbase = (size_t)slot * 1024;
  #pragma unroll
  for (int r = 0; r < 4; ++r) {
    int qr = q0 + w * 16 + g * 4 + r;
    #pragma unroll
    for (int n = 0; n < 4; ++n)
      pout[(rowbase + qr) * 64 + n * 16 + li] = acc_o[n][r];
    if (li == 0) {
      pml[(rowbase + qr) * 2 + 0] = mrow[r];
      pml[(rowbase + qr) * 2 + 1] = lrow[r];
    }
  }
}

// blocks (XCD-chunked over 1152): logical 0..255 quantum, 256..1151 trad
__global__ __launch_bounds__(256) void k_attn_all(
    const unsigned short* __restrict__ qcs, const unsigned short* __restrict__ kcs,
    const unsigned short* __restrict__ xt, const unsigned short* __restrict__ qkv,
    const unsigned short* __restrict__ vt,
    float* __restrict__ pout, float* __restrict__ pml) {
  __shared__ __align__(16) char smem[25600];   // quantum 25600, trad 17408
  int bid = blockIdx.x;
  int l = (bid & 7) * 144 + (bid >> 3);        // 1152 = 8*144
  if (l < 256) {
    int qt = l & 15, h = (l >> 4) & 1, split = l >> 5;     // 8 splits, NT=2
    dev_fattn4<128, 2>(smem, qcs + (size_t)h * SEQ * 128, 128,
                       kcs + (size_t)h * SEQ * 128, 128,
                       xt + (size_t)h * 65536,
                       qt * 64, split * 128, h * 8 + split, pout, pml);
  } else {
    int b2 = l - 256;
    int qt = b2 & 15, hs = b2 >> 4;                        // hs 0..55
    int h = hs % 14, split = hs / 14;                      // 4 splits, NT=4
    dev_fattn4<64, 4>(smem, qkv + h * 64, QKVN,
                      qkv + 896 + h * 64, QKVN,
                      vt + (size_t)h * 65536,
                      qt * 64, split * 256, 16 + h * 4 + split, pout, pml);
  }
}

// ---------------- merge kv-split partials -> concat bf16 ----------------
__global__ __launch_bounds__(256) void k_fmerge(
    const float* __restrict__ pout, const float* __restrict__ pml,
    unsigned short* __restrict__ concat) {
  int rq = blockIdx.x * 4 + (threadIdx.x >> 6);
  int lh = rq >> 10, q = rq & 1023;
  int d = threadIdx.x & 63;
  int s0 = (lh < 2) ? lh * 8 : 16 + (lh - 2) * 4;
  int ns = (lh < 2) ? 8 : 4;
  float m_s[8], l_s[8];
  float M = -1e30f;
  #pragma unroll
  for (int s = 0; s < 8; ++s) {
    if (s < ns) {
      size_t rb = (size_t)(s0 + s) * 1024 + q;
      m_s[s] = pml[rb * 2 + 0];
      l_s[s] = pml[rb * 2 + 1];
      M = fmaxf(M, m_s[s]);
    }
  }
  float num = 0.f, den = 0.f;
  #pragma unroll
  for (int s = 0; s < 8; ++s) {
    if (s < ns) {
      float wgt = __expf((m_s[s] - M) * 0.125f);
      num += wgt * pout[((size_t)(s0 + s) * 1024 + q) * 64 + d];
      den += wgt * l_s[s];
    }
  }
  concat[(size_t)q * DIMX + lh * 64 + d] = f2b_rne(num / den);
}

// ---------------- output projection: 32x64 tiles, 512 blocks, BK=128 ----------------
__global__ __launch_bounds__(256) void k_oproj(
    const unsigned short* __restrict__ A, const unsigned short* __restrict__ B,
    float* __restrict__ C, const float* __restrict__ bias) {
  __shared__ unsigned short As[32 * 128];
  __shared__ unsigned short Bs[64 * 128];
  int bid = blockIdx.x;
  int swz = (bid & 7) * 64 + (bid >> 3);       // 512 = 8*64
  int by = swz >> 4, bx = swz & 15;
  int t = threadIdx.x, lane = t & 63, w = t >> 6;
  int wr = w & 1, wc = w >> 1;
  int g = lane >> 4, li = lane & 15;
  int mb = by * 32, nb = bx * 64;
  int rstg = t >> 4, cs = t & 15;
  f32x4 acc[2] = {};
  for (int kb = 0; kb < DIMX; kb += 128) {
    __syncthreads();
    #pragma unroll
    for (int i = 0; i < 2; ++i) {
      int row = i * 16 + rstg;
      int csw = ((cs ^ (row & 7)) * 8);
      __builtin_amdgcn_global_load_lds(
          (const __attribute__((address_space(1))) unsigned int*)(A + (size_t)(mb + row) * DIMX + kb + csw),
          (__attribute__((address_space(3))) unsigned int*)(As + row * 128 + cs * 8), 16, 0, 0);
    }
    #pragma unroll
    for (int i = 0; i < 4; ++i) {
      int row = i * 16 + rstg;
      int csw = ((cs ^ (row & 7)) * 8);
      __builtin_amdgcn_global_load_lds(
          (const __attribute__((address_space(1))) unsigned int*)(B + (size_t)(nb + row) * DIMX + kb + csw),
          (__attribute__((address_space(3))) unsigned int*)(Bs + row * 128 + cs * 8), 16, 0, 0);
    }
    __syncthreads();
    #pragma unroll
    for (int kk = 0; kk < 4; ++kk) {
      int cb = kk * 4 + g;
      int ra = wr * 16 + li;
      bf16x8 af = *reinterpret_cast<const bf16x8*>(&As[ra * 128 + ((cb ^ (ra & 7)) * 8)]);
      #pragma unroll
      for (int n = 0; n < 2; ++n) {
        int rb = wc * 32 + n * 16 + li;
        bf16x8 bfr = *reinterpret_cast<const bf16x8*>(&Bs[rb * 128 + ((cb ^ (rb & 7)) * 8)]);
        acc[n] = __builtin_amdgcn_mfma_f32_16x16x32_bf16(af, bfr, acc[n], 0, 0, 0);
      }
    }
  }
  int row0 = mb + wr * 16 + g * 4;
  #pragma unroll
  for (int n = 0; n < 2; ++n) {
    int col = nb + wc * 32 + n * 16 + li;
    float bval = bias[col];
    #pragma unroll
    for (int r = 0; r < 4; ++r)
      C[(size_t)(row0 + r) * DIMX + col] = acc[n][r] + bval;
  }
}

extern "C" void kernel_launch(void* const* d_in, const int* in_sizes, int n_in,
                              void* d_out, int out_size, void* d_ws, size_t ws_size,
                              hipStream_t stream) {
  const float* x      = (const float*)d_in[0];
  const float* qsW    = (const float*)d_in[1];
  const float* qsb    = (const float*)d_in[2];
  const float* lng    = (const float*)d_in[3];
  const float* lnb    = (const float*)d_in[4];
  const float* qfreq  = (const float*)d_in[5];
  const float* qshift = (const float*)d_in[6];
  const float* Wq     = (const float*)d_in[7];
  const float* Wk     = (const float*)d_in[8];
  const float* Wv     = (const float*)d_in[9];
  const float* Wo     = (const float*)d_in[10];
  const float* bo     = (const float*)d_in[11];
  float* out = (float*)d_out;

  char* ws = (char*)d_ws;
  size_t off = 0;
  auto alloc = [&](size_t bytes) { char* p = ws + off; off += (bytes + 255) & ~(size_t)255; return p; };
  unsigned short* x_bf      = (unsigned short*)alloc((size_t)SEQ * DIMX * 2);
  unsigned short* wqkv_bf   = (unsigned short*)alloc((size_t)QKVN * DIMX * 2);
  unsigned short* wo_bf     = (unsigned short*)alloc((size_t)DIMX * DIMX * 2);
  unsigned short* concat_bf = (unsigned short*)alloc((size_t)SEQ * DIMX * 2);
  unsigned short* qkv_bf    = (unsigned short*)alloc((size_t)SEQ * QKVN * 2);
  unsigned short* qcs       = (unsigned short*)alloc((size_t)QH * SEQ * 128 * 2);
  unsigned short* kcs       = (unsigned short*)alloc((size_t)QH * SEQ * 128 * 2);
  unsigned short* vt        = (unsigned short*)alloc((size_t)TH * HD * SEQ * 2);
  unsigned short* xt        = (unsigned short*)alloc((size_t)QH * HD * SEQ * 2);
  float*          pout      = (float*)alloc((size_t)72 * SEQ * 64 * 4);
  float*          pml       = (float*)alloc((size_t)72 * SEQ * 2 * 4);

  // 1. prep: converts + quantum prep + x^T
  k_prep<<<NB_F2B + NB_QPREP + NB_XT, 256, 0, stream>>>(
      x, qsW, qsb, lng, lnb, qfreq, qshift, Wq, Wk, Wv, Wo,
      x_bf, wqkv_bf, wo_bf, qcs, kcs, xt);

  // 2. QKV projection (V tiles straight to vt transposed)
  k_qkv<<<672, 256, 0, stream>>>(x_bf, wqkv_bf, qkv_bf, vt);

  // 3. all attention (quantum + trad), m97-style staging
  k_attn_all<<<1152, 256, 0, stream>>>(qcs, kcs, xt, qkv_bf, vt, pout, pml);

  // 4. merge partials
  k_fmerge<<<16 * SEQ / 4, 256, 0, stream>>>(pout, pml, concat_bf);

  // 5. output projection + bias
  k_oproj<<<512, 256, 0, stream>>>(concat_bf, wo_bf, out, bo);
}

// Round 19
// 73.399 us; speedup vs baseline: 1.0790x; 1.0035x over previous
//
#include <hip/hip_runtime.h>
#include <hip/hip_bf16.h>
#include <math.h>

#define DIMX 1024
#define SEQ  1024
#define HD   64
#define QH   2
#define TH   14
#define QKVN 2688   // 3*896
#define LN_EPS 1e-5f
#define NB_F2B 4736
#define NB_QPREP 1024
#define NB_XT 32

typedef __bf16 bf16x8 __attribute__((ext_vector_type(8)));
typedef float  f32x4  __attribute__((ext_vector_type(4)));
typedef unsigned short u16x8 __attribute__((ext_vector_type(8)));

__device__ inline unsigned short f2b_rne(float f) {
  unsigned int u = __float_as_uint(f);
  unsigned int r = (u + 0x7FFF + ((u >> 16) & 1)) >> 16;
  return (unsigned short)r;
}

__device__ inline float waveRedSum(float v) {
  #pragma unroll
  for (int off = 32; off; off >>= 1) v += __shfl_xor(v, off, 64);
  return v;
}

// ---------------- prep: f2b converts | quantum prep | x^T for quantum V ----------------
__global__ __launch_bounds__(256) void k_prep(
    const float* __restrict__ x, const float* __restrict__ qsW,
    const float* __restrict__ qsb, const float* __restrict__ lng,
    const float* __restrict__ lnb, const float* __restrict__ qfreq,
    const float* __restrict__ qshift,
    const float* __restrict__ wq, const float* __restrict__ wk,
    const float* __restrict__ wv, const float* __restrict__ wo,
    unsigned short* __restrict__ x_bf, unsigned short* __restrict__ wqkv_bf,
    unsigned short* __restrict__ wo_bf,
    unsigned short* __restrict__ qcs, unsigned short* __restrict__ kcs,
    unsigned short* __restrict__ xt) {
  __shared__ float xrow2[2][HD];
  __shared__ float redm[2][2], redv[2][2];
  __shared__ float qsv2[2][128];
  __shared__ unsigned short ttile[64][72];
  int t = threadIdx.x;
  int bid = blockIdx.x;
  if (bid < NB_F2B) {
    long i = ((long)bid * 256 + t) * 4;
    float4 v;
    unsigned short* dst;
    if (i < 1048576) {
      v = *reinterpret_cast<const float4*>(x + i);
      dst = x_bf + i;
    } else if (i < 3801088) {
      long j = i - 1048576;
      const float* s = (j < 917504) ? wq + j
                     : (j < 1835008) ? wk + (j - 917504)
                                     : wv + (j - 1835008);
      v = *reinterpret_cast<const float4*>(s);
      dst = wqkv_bf + j;
    } else {
      long j = i - 3801088;
      v = *reinterpret_cast<const float4*>(wo + j);
      dst = wo_bf + j;
    }
    ushort4 o;
    o.x = f2b_rne(v.x); o.y = f2b_rne(v.y); o.z = f2b_rne(v.z); o.w = f2b_rne(v.w);
    *reinterpret_cast<ushort4*>(dst) = o;
  } else if (bid < NB_F2B + NB_QPREP) {
    int half = t >> 7, o = t & 127;
    int row = (bid - NB_F2B) * 2 + half;
    int h = row >> 10, i = row & 1023;
    if (o < HD) xrow2[half][o] = x[i * DIMX + h * HD + o];
    __syncthreads();
    float s = qsb[o];
    #pragma unroll
    for (int d = 0; d < HD; d += 4) {
      float4 w = *reinterpret_cast<const float4*>(qsW + o * HD + d);
      float4 xv = *reinterpret_cast<const float4*>(&xrow2[half][d]);
      s += xv.x * w.x + xv.y * w.y + xv.z * w.z + xv.w * w.w;
    }
    int wid = (o >> 6), lane = o & 63;
    float ws = waveRedSum(s);
    if (lane == 0) redm[half][wid] = ws;
    __syncthreads();
    float mu = (redm[half][0] + redm[half][1]) * (1.0f / 128.0f);
    float dv = s - mu;
    float ws2 = waveRedSum(dv * dv);
    if (lane == 0) redv[half][wid] = ws2;
    __syncthreads();
    float var = (redv[half][0] + redv[half][1]) * (1.0f / 128.0f);
    float y = dv * rsqrtf(var + LN_EPS) * lng[o] + lnb[o];
    qsv2[half][o] = tanhf(y);
    __syncthreads();
    float freq = qfreq[h], shift = qshift[h];
    size_t base = ((size_t)h * 1024 + i) * 128;
    if (o < HD) {
      float amp = qsv2[half][o];
      float a = qsv2[half][64 + o] * freq + shift;
      float sn, cs;
      __sincosf(a, &sn, &cs);
      qcs[base + o]      = f2b_rne(amp * cs);
      qcs[base + 64 + o] = f2b_rne(amp * sn);
    } else {
      int d = o - 64;
      float amp = qsv2[half][d];
      float bAng = qsv2[half][64 + d] * freq;
      float sn, cs;
      __sincosf(bAng, &sn, &cs);
      kcs[base + d]      = f2b_rne(amp * cs);
      kcs[base + 64 + d] = f2b_rne(amp * sn);
    }
  } else {
    int b = bid - (NB_F2B + NB_QPREP);
    int h = b >> 4, kv0 = (b & 15) * 64;
    #pragma unroll
    for (int pass = 0; pass < 2; ++pass) {
      int s = pass * 256 + t;
      int r = s >> 3, c8 = (s & 7) * 8;
      const float* src = x + (size_t)(kv0 + r) * DIMX + h * 64 + c8;
      float4 a = *reinterpret_cast<const float4*>(src);
      float4 b4 = *reinterpret_cast<const float4*>(src + 4);
      ushort4 o1, o2;
      o1.x = f2b_rne(a.x);  o1.y = f2b_rne(a.y);  o1.z = f2b_rne(a.z);  o1.w = f2b_rne(a.w);
      o2.x = f2b_rne(b4.x); o2.y = f2b_rne(b4.y); o2.z = f2b_rne(b4.z); o2.w = f2b_rne(b4.w);
      *reinterpret_cast<ushort4*>(&ttile[r][c8]) = o1;
      *reinterpret_cast<ushort4*>(&ttile[r][c8 + 4]) = o2;
    }
    __syncthreads();
    #pragma unroll
    for (int pass = 0; pass < 2; ++pass) {
      int s = pass * 256 + t;
      int d = s >> 3, k8 = (s & 7) * 8;
      u16x8 o;
      #pragma unroll
      for (int j = 0; j < 8; ++j) o[j] = ttile[k8 + j][d];
      *reinterpret_cast<u16x8*>(xt + (size_t)h * 65536 + (size_t)d * 1024 + kv0 + k8) = o;
    }
  }
}

// ---------------- 64x64 GEMM device body: BK=128, global_load_lds + 16-slot swizzle --
template <int HAS_BIAS, int BF16_OUT>
__device__ __forceinline__ void dev_gemm64(
    char* smem,
    const unsigned short* __restrict__ A, const unsigned short* __restrict__ B,
    void* __restrict__ Cv, const float* __restrict__ bias,
    unsigned short* __restrict__ vtp,
    int bx, int by, int K, int lda, int ldb, int ldc) {
  unsigned short* As = (unsigned short*)smem;     // [64][128]
  unsigned short* Bs = As + 64 * 128;
  int t = threadIdx.x, lane = t & 63, w = t >> 6;
  int wr = w >> 1, wc = w & 1;
  int g = lane >> 4, li = lane & 15;
  int mb = by * 64, nb = bx * 64;
  int rstg = t >> 4;            // 0..15
  int cs = t & 15;              // col16 slot
  f32x4 acc[2][2] = {};
  for (int kb = 0; kb < K; kb += 128) {
    __syncthreads();
    #pragma unroll
    for (int i = 0; i < 4; ++i) {
      int row = i * 16 + rstg;
      int csw = ((cs ^ (row & 7)) * 8);
      __builtin_amdgcn_global_load_lds(
          (const __attribute__((address_space(1))) unsigned int*)(A + (size_t)(mb + row) * lda + kb + csw),
          (__attribute__((address_space(3))) unsigned int*)(As + row * 128 + cs * 8), 16, 0, 0);
      __builtin_amdgcn_global_load_lds(
          (const __attribute__((address_space(1))) unsigned int*)(B + (size_t)(nb + row) * ldb + kb + csw),
          (__attribute__((address_space(3))) unsigned int*)(Bs + row * 128 + cs * 8), 16, 0, 0);
    }
    __syncthreads();
    #pragma unroll
    for (int kk = 0; kk < 4; ++kk) {
      bf16x8 af[2], bfr[2];
      #pragma unroll
      for (int m = 0; m < 2; ++m) {
        int r = wr * 32 + m * 16 + li;
        int cb = kk * 4 + g;
        af[m] = *reinterpret_cast<const bf16x8*>(&As[r * 128 + ((cb ^ (r & 7)) * 8)]);
      }
      #pragma unroll
      for (int n = 0; n < 2; ++n) {
        int r = wc * 32 + n * 16 + li;
        int cb = kk * 4 + g;
        bfr[n] = *reinterpret_cast<const bf16x8*>(&Bs[r * 128 + ((cb ^ (r & 7)) * 8)]);
      }
      #pragma unroll
      for (int m = 0; m < 2; ++m)
        #pragma unroll
        for (int n = 0; n < 2; ++n)
          acc[m][n] = __builtin_amdgcn_mfma_f32_16x16x32_bf16(af[m], bfr[n], acc[m][n], 0, 0, 0);
    }
  }
  if (vtp != nullptr && nb >= 1792) {
    #pragma unroll
    for (int m = 0; m < 2; ++m) {
      int row0 = mb + wr * 32 + m * 16 + g * 4;
      #pragma unroll
      for (int n = 0; n < 2; ++n) {
        int colrel = nb - 1792 + wc * 32 + n * 16 + li;
        #pragma unroll
        for (int r = 0; r < 4; ++r)
          vtp[(size_t)colrel * 1024 + row0 + r] = f2b_rne(acc[m][n][r]);
      }
    }
    return;
  }
  #pragma unroll
  for (int m = 0; m < 2; ++m) {
    int row0 = mb + wr * 32 + m * 16 + g * 4;
    #pragma unroll
    for (int n = 0; n < 2; ++n) {
      int col = nb + wc * 32 + n * 16 + li;
      float bval = HAS_BIAS ? bias[col] : 0.0f;
      #pragma unroll
      for (int r = 0; r < 4; ++r) {
        size_t idx = (size_t)(row0 + r) * ldc + col;
        if (BF16_OUT) ((unsigned short*)Cv)[idx] = f2b_rne(acc[m][n][r] + bval);
        else          ((float*)Cv)[idx] = acc[m][n][r] + bval;
      }
    }
  }
}

// ---------------- QKV GEMM (672 blocks, XCD-chunked; V tiles -> vt transposed) -------
__global__ __launch_bounds__(256) void k_qkv(
    const unsigned short* __restrict__ x_bf, const unsigned short* __restrict__ wqkv,
    unsigned short* __restrict__ qkv, unsigned short* __restrict__ vt) {
  __shared__ __align__(16) char smem[32768];
  int bid = blockIdx.x;
  int swz = (bid & 7) * 84 + (bid >> 3);       // 672 = 8*84
  int by = swz / 42, bx = swz % 42;
  dev_gemm64<0, 1>(smem, x_bf, wqkv, qkv, nullptr, vt, bx, by, DIMX, DIMX, DIMX, QKVN);
}

// ---------------- attention (quantum path): m97-style single-buffer, __syncthreads ---
template <int DQK, int NT>
__device__ __forceinline__ void dev_fattn4(
    char* smem,
    const unsigned short* __restrict__ Qp, int ldq,
    const unsigned short* __restrict__ Kp, int ldk,
    const unsigned short* __restrict__ Vp,       // [64][1024] bf16 (d-major)
    int q0, int kv0, int slot,
    float* __restrict__ pout, float* __restrict__ pml) {
  const int KREG = DQK / 32;
  const int NSLOT = DQK / 8;
  unsigned short* Ks = (unsigned short*)smem;  // [64][DQK]; V tile reuses as [64][64]
  unsigned short* Ps = Ks + 64 * DQK;          // [64][72]
  int t = threadIdx.x, lane = t & 63, w = t >> 6;
  int g = lane >> 4, li = lane & 15;

  bf16x8 aq[KREG];
  #pragma unroll
  for (int kk = 0; kk < KREG; ++kk)
    aq[kk] = *reinterpret_cast<const bf16x8*>(
        Qp + (size_t)(q0 + w * 16 + li) * ldq + kk * 32 + g * 8);

  f32x4 s_all[NT][4] = {};

  {
    int rstg = t / NSLOT, cs = t % NSLOT;
    #pragma unroll
    for (int tile = 0; tile < NT; ++tile) {
      int j0 = kv0 + tile * 64;
      __syncthreads();
      #pragma unroll
      for (int i = 0; i < NSLOT / 4; ++i) {
        int row = i * (256 / NSLOT) + rstg;
        int csw = ((cs ^ (row & 7)) * 8);
        __builtin_amdgcn_global_load_lds(
            (const __attribute__((address_space(1))) unsigned int*)(Kp + (size_t)(j0 + row) * ldk + csw),
            (__attribute__((address_space(3))) unsigned int*)(Ks + row * DQK + cs * 8), 16, 0, 0);
      }
      __syncthreads();
      #pragma unroll
      for (int kk = 0; kk < KREG; ++kk) {
        #pragma unroll
        for (int n = 0; n < 4; ++n) {
          int r = n * 16 + li;
          int cb = kk * 4 + g;
          bf16x8 bk = *reinterpret_cast<const bf16x8*>(&Ks[r * DQK + ((cb ^ (r & 7)) * 8)]);
          s_all[tile][n] = __builtin_amdgcn_mfma_f32_16x16x32_bf16(aq[kk], bk, s_all[tile][n], 0, 0, 0);
        }
      }
    }
  }

  float mrow[4], lrow[4];
  #pragma unroll
  for (int r = 0; r < 4; ++r) {
    float tm = -1e30f;
    #pragma unroll
    for (int tile = 0; tile < NT; ++tile)
      #pragma unroll
      for (int n = 0; n < 4; ++n) tm = fmaxf(tm, s_all[tile][n][r]);
    #pragma unroll
    for (int m = 1; m < 16; m <<= 1) tm = fmaxf(tm, __shfl_xor(tm, m, 64));
    float rs = 0.f;
    #pragma unroll
    for (int tile = 0; tile < NT; ++tile)
      #pragma unroll
      for (int n = 0; n < 4; ++n) {
        float p = __expf((s_all[tile][n][r] - tm) * 0.125f);
        s_all[tile][n][r] = p;
        rs += p;
      }
    #pragma unroll
    for (int m = 1; m < 16; m <<= 1) rs += __shfl_xor(rs, m, 64);
    mrow[r] = tm; lrow[r] = rs;
  }

  f32x4 acc_o[4] = {};
  {
    int rstg = t >> 3, cs = t & 7;
    #pragma unroll
    for (int tile = 0; tile < NT; ++tile) {
      int j0 = kv0 + tile * 64;
      __syncthreads();
      #pragma unroll
      for (int i = 0; i < 2; ++i) {
        int row = i * 32 + rstg;
        int csw = ((cs ^ (row & 7)) * 8);
        __builtin_amdgcn_global_load_lds(
            (const __attribute__((address_space(1))) unsigned int*)(Vp + (size_t)row * 1024 + j0 + csw),
            (__attribute__((address_space(3))) unsigned int*)(Ks + row * 64 + cs * 8), 16, 0, 0);
      }
      __syncthreads();
      #pragma unroll
      for (int n = 0; n < 4; ++n)
        #pragma unroll
        for (int r = 0; r < 4; ++r)
          Ps[(w * 16 + g * 4 + r) * 72 + n * 16 + li] = f2b_rne(s_all[tile][n][r]);
      #pragma unroll
      for (int kk = 0; kk < 2; ++kk) {
        bf16x8 ap = *reinterpret_cast<const bf16x8*>(&Ps[(w * 16 + li) * 72 + kk * 32 + g * 8]);
        #pragma unroll
        for (int n = 0; n < 4; ++n) {
          int r = n * 16 + li;
          int cb = kk * 4 + g;
          bf16x8 bv = *reinterpret_cast<const bf16x8*>(&Ks[r * 64 + ((cb ^ (r & 7)) * 8)]);
          acc_o[n] = __builtin_amdgcn_mfma_f32_16x16x32_bf16(ap, bv, acc_o[n], 0, 0, 0);
        }
      }
    }
  }

  size_t rowbase = (size_t)slot * 1024;
  #pragma unroll
  for (int r = 0; r < 4; ++r) {
    int qr = q0 + w * 16 + g * 4 + r;
    #pragma unroll
    for (int n = 0; n < 4; ++n)
      pout[(rowbase + qr) * 64 + n * 16 + li] = acc_o[n][r];
    if (li == 0) {
      pml[(rowbase + qr) * 2 + 0] = mrow[r];
      pml[(rowbase + qr) * 2 + 1] = lrow[r];
    }
  }
}

// ---------------- attention (trad path): double-buffered, counted-vmcnt pipeline -----
// Stage chain K0..K3,V0..V3 runs 2-deep: issue(t+1) flies during compute(t).
// Raw s_barrier (no vmcnt(0) drain) + counted s_waitcnt vmcnt(2); sched_barrier(0)
// pins ordering per rule #18. Buffers B0/B1 8KB each; Ps wave-local.
#define ISSUE_K(TILE, BUF) { \
  int j0_ = kv0 + (TILE) * 64; \
  _Pragma("unroll") \
  for (int i_ = 0; i_ < 2; ++i_) { \
    int row_ = i_ * 32 + rk; \
    int csw_ = ((ck ^ (row_ & 7)) * 8); \
    __builtin_amdgcn_global_load_lds( \
        (const __attribute__((address_space(1))) unsigned int*)(Kp + (size_t)(j0_ + row_) * ldk + csw_), \
        (__attribute__((address_space(3))) unsigned int*)((BUF) + row_ * 64 + ck * 8), 16, 0, 0); \
  } }

#define ISSUE_V(TILE, BUF) { \
  int j0_ = kv0 + (TILE) * 64; \
  _Pragma("unroll") \
  for (int i_ = 0; i_ < 2; ++i_) { \
    int row_ = i_ * 32 + rk; \
    int csw_ = ((ck ^ (row_ & 7)) * 8); \
    __builtin_amdgcn_global_load_lds( \
        (const __attribute__((address_space(1))) unsigned int*)(Vp + (size_t)row_ * 1024 + j0_ + csw_), \
        (__attribute__((address_space(3))) unsigned int*)((BUF) + row_ * 64 + ck * 8), 16, 0, 0); \
  } }

#define MFMA_K(TILE, BUF) { \
  _Pragma("unroll") \
  for (int kk_ = 0; kk_ < 2; ++kk_) { \
    _Pragma("unroll") \
    for (int n_ = 0; n_ < 4; ++n_) { \
      int r_ = n_ * 16 + li; \
      int cb_ = kk_ * 4 + g; \
      bf16x8 bk_ = *reinterpret_cast<const bf16x8*>(&(BUF)[r_ * 64 + ((cb_ ^ (r_ & 7)) * 8)]); \
      s_all[TILE][n_] = __builtin_amdgcn_mfma_f32_16x16x32_bf16(aq[kk_], bk_, s_all[TILE][n_], 0, 0, 0); \
    } } }

#define PV_T(TILE, BUF) { \
  _Pragma("unroll") \
  for (int n4_ = 0; n4_ < 4; ++n4_) \
    _Pragma("unroll") \
    for (int r_ = 0; r_ < 4; ++r_) \
      Ps[(w * 16 + g * 4 + r_) * 72 + n4_ * 16 + li] = f2b_rne(s_all[TILE][n4_][r_]); \
  _Pragma("unroll") \
  for (int kk_ = 0; kk_ < 2; ++kk_) { \
    bf16x8 ap_ = *reinterpret_cast<const bf16x8*>(&Ps[(w * 16 + li) * 72 + kk_ * 32 + g * 8]); \
    _Pragma("unroll") \
    for (int n_ = 0; n_ < 4; ++n_) { \
      int r_ = n_ * 16 + li; \
      int cb_ = kk_ * 4 + g; \
      bf16x8 bv_ = *reinterpret_cast<const bf16x8*>(&(BUF)[r_ * 64 + ((cb_ ^ (r_ & 7)) * 8)]); \
      acc_o[n_] = __builtin_amdgcn_mfma_f32_16x16x32_bf16(ap_, bv_, acc_o[n_], 0, 0, 0); \
    } } }

#define WAITBAR2() { asm volatile("s_waitcnt vmcnt(2)" ::: "memory"); \
  __builtin_amdgcn_sched_barrier(0); __builtin_amdgcn_s_barrier(); \
  __builtin_amdgcn_sched_barrier(0); }
#define WAITBAR0() { asm volatile("s_waitcnt vmcnt(0)" ::: "memory"); \
  __builtin_amdgcn_sched_barrier(0); __builtin_amdgcn_s_barrier(); \
  __builtin_amdgcn_sched_barrier(0); }
#define REBAR() { __builtin_amdgcn_sched_barrier(0); __builtin_amdgcn_s_barrier(); \
  __builtin_amdgcn_sched_barrier(0); }

__device__ __forceinline__ void dev_fattn_db(
    char* smem,
    const unsigned short* __restrict__ Qp, int ldq,
    const unsigned short* __restrict__ Kp, int ldk,
    const unsigned short* __restrict__ Vp,
    int q0, int kv0, int slot,
    float* __restrict__ pout, float* __restrict__ pml) {
  unsigned short* B0 = (unsigned short*)smem;        // 8 KB
  unsigned short* B1 = B0 + 4096;                    // 8 KB
  unsigned short* Ps = B0 + 8192;                    // [64][72] = 9.2 KB
  int t = threadIdx.x, lane = t & 63, w = t >> 6;
  int g = lane >> 4, li = lane & 15;
  int rk = t >> 3, ck = t & 7;                       // stage thread map (2 glds/thread)

  bf16x8 aq[2];
  #pragma unroll
  for (int kk = 0; kk < 2; ++kk)
    aq[kk] = *reinterpret_cast<const bf16x8*>(
        Qp + (size_t)(q0 + w * 16 + li) * ldq + kk * 32 + g * 8);

  f32x4 s_all[4][4] = {};
  f32x4 acc_o[4] = {};

  ISSUE_K(0, B0);
  ISSUE_K(1, B1);

  WAITBAR2(); MFMA_K(0, B0); REBAR(); ISSUE_K(2, B0);
  WAITBAR2(); MFMA_K(1, B1); REBAR(); ISSUE_K(3, B1);
  WAITBAR2(); MFMA_K(2, B0); REBAR(); ISSUE_V(0, B0);
  WAITBAR2(); MFMA_K(3, B1); REBAR(); ISSUE_V(1, B1);

  // softmax (registers only — overlaps V0/V1 flight)
  float mrow[4], lrow[4];
  #pragma unroll
  for (int r = 0; r < 4; ++r) {
    float tm = -1e30f;
    #pragma unroll
    for (int tile = 0; tile < 4; ++tile)
      #pragma unroll
      for (int n = 0; n < 4; ++n) tm = fmaxf(tm, s_all[tile][n][r]);
    #pragma unroll
    for (int m = 1; m < 16; m <<= 1) tm = fmaxf(tm, __shfl_xor(tm, m, 64));
    float rs = 0.f;
    #pragma unroll
    for (int tile = 0; tile < 4; ++tile)
      #pragma unroll
      for (int n = 0; n < 4; ++n) {
        float p = __expf((s_all[tile][n][r] - tm) * 0.125f);
        s_all[tile][n][r] = p;
        rs += p;
      }
    #pragma unroll
    for (int m = 1; m < 16; m <<= 1) rs += __shfl_xor(rs, m, 64);
    mrow[r] = tm; lrow[r] = rs;
  }

  WAITBAR2(); PV_T(0, B0); REBAR(); ISSUE_V(2, B0);
  WAITBAR2(); PV_T(1, B1); REBAR(); ISSUE_V(3, B1);
  WAITBAR2(); PV_T(2, B0);
  WAITBAR0(); PV_T(3, B1);

  size_t rowbase = (size_t)slot * 1024;
  #pragma unroll
  for (int r = 0; r < 4; ++r) {
    int qr = q0 + w * 16 + g * 4 + r;
    #pragma unroll
    for (int n = 0; n < 4; ++n)
      pout[(rowbase + qr) * 64 + n * 16 + li] = acc_o[n][r];
    if (li == 0) {
      pml[(rowbase + qr) * 2 + 0] = mrow[r];
      pml[(rowbase + qr) * 2 + 1] = lrow[r];
    }
  }
}

// blocks (XCD-chunked over 1152): logical 0..255 quantum, 256..1151 trad
__global__ __launch_bounds__(256) void k_attn_all(
    const unsigned short* __restrict__ qcs, const unsigned short* __restrict__ kcs,
    const unsigned short* __restrict__ xt, const unsigned short* __restrict__ qkv,
    const unsigned short* __restrict__ vt,
    float* __restrict__ pout, float* __restrict__ pml) {
  __shared__ __align__(16) char smem[25600];   // quantum 25.6 KB, trad dbuf 25.2 KB
  int bid = blockIdx.x;
  int l = (bid & 7) * 144 + (bid >> 3);        // 1152 = 8*144
  if (l < 256) {
    int qt = l & 15, h = (l >> 4) & 1, split = l >> 5;     // 8 splits, NT=2
    dev_fattn4<128, 2>(smem, qcs + (size_t)h * SEQ * 128, 128,
                       kcs + (size_t)h * SEQ * 128, 128,
                       xt + (size_t)h * 65536,
                       qt * 64, split * 128, h * 8 + split, pout, pml);
  } else {
    int b2 = l - 256;
    int qt = b2 & 15, hs = b2 >> 4;                        // hs 0..55
    int h = hs % 14, split = hs / 14;                      // 4 splits, NT=4
    dev_fattn_db(smem, qkv + h * 64, QKVN,
                 qkv + 896 + h * 64, QKVN,
                 vt + (size_t)h * 65536,
                 qt * 64, split * 256, 16 + h * 4 + split, pout, pml);
  }
}

// ---------------- merge kv-split partials -> concat bf16 ----------------
__global__ __launch_bounds__(256) void k_fmerge(
    const float* __restrict__ pout, const float* __restrict__ pml,
    unsigned short* __restrict__ concat) {
  int rq = blockIdx.x * 4 + (threadIdx.x >> 6);
  int lh = rq >> 10, q = rq & 1023;
  int d = threadIdx.x & 63;
  int s0 = (lh < 2) ? lh * 8 : 16 + (lh - 2) * 4;
  int ns = (lh < 2) ? 8 : 4;
  float m_s[8], l_s[8];
  float M = -1e30f;
  #pragma unroll
  for (int s = 0; s < 8; ++s) {
    if (s < ns) {
      size_t rb = (size_t)(s0 + s) * 1024 + q;
      m_s[s] = pml[rb * 2 + 0];
      l_s[s] = pml[rb * 2 + 1];
      M = fmaxf(M, m_s[s]);
    }
  }
  float num = 0.f, den = 0.f;
  #pragma unroll
  for (int s = 0; s < 8; ++s) {
    if (s < ns) {
      float wgt = __expf((m_s[s] - M) * 0.125f);
      num += wgt * pout[((size_t)(s0 + s) * 1024 + q) * 64 + d];
      den += wgt * l_s[s];
    }
  }
  concat[(size_t)q * DIMX + lh * 64 + d] = f2b_rne(num / den);
}

// ---------------- output projection: 32x64 tiles, 512 blocks, BK=128 ----------------
__global__ __launch_bounds__(256) void k_oproj(
    const unsigned short* __restrict__ A, const unsigned short* __restrict__ B,
    float* __restrict__ C, const float* __restrict__ bias) {
  __shared__ unsigned short As[32 * 128];
  __shared__ unsigned short Bs[64 * 128];
  int bid = blockIdx.x;
  int swz = (bid & 7) * 64 + (bid >> 3);       // 512 = 8*64
  int by = swz >> 4, bx = swz & 15;
  int t = threadIdx.x, lane = t & 63, w = t >> 6;
  int wr = w & 1, wc = w >> 1;
  int g = lane >> 4, li = lane & 15;
  int mb = by * 32, nb = bx * 64;
  int rstg = t >> 4, cs = t & 15;
  f32x4 acc[2] = {};
  for (int kb = 0; kb < DIMX; kb += 128) {
    __syncthreads();
    #pragma unroll
    for (int i = 0; i < 2; ++i) {
      int row = i * 16 + rstg;
      int csw = ((cs ^ (row & 7)) * 8);
      __builtin_amdgcn_global_load_lds(
          (const __attribute__((address_space(1))) unsigned int*)(A + (size_t)(mb + row) * DIMX + kb + csw),
          (__attribute__((address_space(3))) unsigned int*)(As + row * 128 + cs * 8), 16, 0, 0);
    }
    #pragma unroll
    for (int i = 0; i < 4; ++i) {
      int row = i * 16 + rstg;
      int csw = ((cs ^ (row & 7)) * 8);
      __builtin_amdgcn_global_load_lds(
          (const __attribute__((address_space(1))) unsigned int*)(B + (size_t)(nb + row) * DIMX + kb + csw),
          (__attribute__((address_space(3))) unsigned int*)(Bs + row * 128 + cs * 8), 16, 0, 0);
    }
    __syncthreads();
    #pragma unroll
    for (int kk = 0; kk < 4; ++kk) {
      int cb = kk * 4 + g;
      int ra = wr * 16 + li;
      bf16x8 af = *reinterpret_cast<const bf16x8*>(&As[ra * 128 + ((cb ^ (ra & 7)) * 8)]);
      #pragma unroll
      for (int n = 0; n < 2; ++n) {
        int rb = wc * 32 + n * 16 + li;
        bf16x8 bfr = *reinterpret_cast<const bf16x8*>(&Bs[rb * 128 + ((cb ^ (rb & 7)) * 8)]);
        acc[n] = __builtin_amdgcn_mfma_f32_16x16x32_bf16(af, bfr, acc[n], 0, 0, 0);
      }
    }
  }
  int row0 = mb + wr * 16 + g * 4;
  #pragma unroll
  for (int n = 0; n < 2; ++n) {
    int col = nb + wc * 32 + n * 16 + li;
    float bval = bias[col];
    #pragma unroll
    for (int r = 0; r < 4; ++r)
      C[(size_t)(row0 + r) * DIMX + col] = acc[n][r] + bval;
  }
}

extern "C" void kernel_launch(void* const* d_in, const int* in_sizes, int n_in,
                              void* d_out, int out_size, void* d_ws, size_t ws_size,
                              hipStream_t stream) {
  const float* x      = (const float*)d_in[0];
  const float* qsW    = (const float*)d_in[1];
  const float* qsb    = (const float*)d_in[2];
  const float* lng    = (const float*)d_in[3];
  const float* lnb    = (const float*)d_in[4];
  const float* qfreq  = (const float*)d_in[5];
  const float* qshift = (const float*)d_in[6];
  const float* Wq     = (const float*)d_in[7];
  const float* Wk     = (const float*)d_in[8];
  const float* Wv     = (const float*)d_in[9];
  const float* Wo     = (const float*)d_in[10];
  const float* bo     = (const float*)d_in[11];
  float* out = (float*)d_out;

  char* ws = (char*)d_ws;
  size_t off = 0;
  auto alloc = [&](size_t bytes) { char* p = ws + off; off += (bytes + 255) & ~(size_t)255; return p; };
  unsigned short* x_bf      = (unsigned short*)alloc((size_t)SEQ * DIMX * 2);
  unsigned short* wqkv_bf   = (unsigned short*)alloc((size_t)QKVN * DIMX * 2);
  unsigned short* wo_bf     = (unsigned short*)alloc((size_t)DIMX * DIMX * 2);
  unsigned short* concat_bf = (unsigned short*)alloc((size_t)SEQ * DIMX * 2);
  unsigned short* qkv_bf    = (unsigned short*)alloc((size_t)SEQ * QKVN * 2);
  unsigned short* qcs       = (unsigned short*)alloc((size_t)QH * SEQ * 128 * 2);
  unsigned short* kcs       = (unsigned short*)alloc((size_t)QH * SEQ * 128 * 2);
  unsigned short* vt        = (unsigned short*)alloc((size_t)TH * HD * SEQ * 2);
  unsigned short* xt        = (unsigned short*)alloc((size_t)QH * HD * SEQ * 2);
  float*          pout      = (float*)alloc((size_t)72 * SEQ * 64 * 4);
  float*          pml       = (float*)alloc((size_t)72 * SEQ * 2 * 4);

  // 1. prep: converts + quantum prep + x^T
  k_prep<<<NB_F2B + NB_QPREP + NB_XT, 256, 0, stream>>>(
      x, qsW, qsb, lng, lnb, qfreq, qshift, Wq, Wk, Wv, Wo,
      x_bf, wqkv_bf, wo_bf, qcs, kcs, xt);

  // 2. QKV projection (V tiles straight to vt transposed)
  k_qkv<<<672, 256, 0, stream>>>(x_bf, wqkv_bf, qkv_bf, vt);

  // 3. all attention: quantum single-buffer, trad counted-vmcnt dbuf pipeline
  k_attn_all<<<1152, 256, 0, stream>>>(qcs, kcs, xt, qkv_bf, vt, pout, pml);

  // 4. merge partials
  k_fmerge<<<16 * SEQ / 4, 256, 0, stream>>>(pout, pml, concat_bf);

  // 5. output projection + bias
  k_oproj<<<512, 256, 0, stream>>>(concat_bf, wo_bf, out, bo);
}